// Round 1
// baseline (1323.650 us; speedup 1.0000x reference)
//
#include <hip/hip_runtime.h>
#include <stdint.h>

#define N_TOK 8192
#define C_DIM 1024
#define H_DIM 4096
#define N_EXP 8

typedef __bf16 bf16x8 __attribute__((ext_vector_type(8)));
typedef float floatx4 __attribute__((ext_vector_type(4)));

__device__ __forceinline__ short f2b(float f) {
    unsigned u = __float_as_uint(f);
    unsigned r = (u + 0x7FFFu + ((u >> 16) & 1u)) >> 16;
    return (short)(r & 0xFFFFu);
}

__device__ __forceinline__ float gelu_f(float x) {
    const float c = 0.7978845608028654f;  // sqrt(2/pi)
    float u = c * (x + 0.044715f * x * x * x);
    float a = fabsf(u);
    float e = __expf(-2.0f * a);
    float t = (1.0f - e) / (1.0f + e);  // tanh(|u|), safe for large |u|
    return 0.5f * x * (1.0f + copysignf(t, u));
}

// ---------------- cast x (fp32 -> bf16 bits) ----------------
__global__ void cast_x_k(const float* __restrict__ in, short* __restrict__ out) {
    int i = (blockIdx.x * 256 + threadIdx.x) * 4;
    float4 v = *(const float4*)(in + i);
    short4 o;
    o.x = f2b(v.x); o.y = f2b(v.y); o.z = f2b(v.z); o.w = f2b(v.w);
    *(short4*)(out + i) = o;
}

// ------------- transpose + cast weights: W[K,N] fp32 -> WT[N,K] bf16 -------------
__global__ void transpose_cast_k(const float* __restrict__ W, short* __restrict__ WT,
                                 int K, int N) {
    __shared__ float tile[32][33];
    size_t moff = (size_t)blockIdx.z * (size_t)K * (size_t)N;
    int n0 = blockIdx.x * 32, k0 = blockIdx.y * 32;
    int tx = threadIdx.x, ty = threadIdx.y;  // (32, 8)
#pragma unroll
    for (int j = 0; j < 32; j += 8)
        tile[ty + j][tx] = W[moff + (size_t)(k0 + ty + j) * N + n0 + tx];
    __syncthreads();
#pragma unroll
    for (int j = 0; j < 32; j += 8)
        WT[moff + (size_t)(n0 + ty + j) * K + k0 + tx] = f2b(tile[tx][ty + j]);
}

// ---------------- router: logits, softmax, top2, expert lists ----------------
__global__ void router_k(const float* __restrict__ x, const float* __restrict__ Wr,
                         int* __restrict__ counts, int* __restrict__ tok_list,
                         float* __restrict__ gate_list, int* __restrict__ ent) {
    int token = blockIdx.x * 4 + (threadIdx.x >> 6);
    int lane = threadIdx.x & 63;
    const float* xr = x + (size_t)token * C_DIM;
    float p[8];
#pragma unroll
    for (int e = 0; e < 8; ++e) p[e] = 0.f;
    for (int jj = 0; jj < 4; ++jj) {
        int c = (jj * 64 + lane) * 4;
        float4 xv = *(const float4*)(xr + c);
        const float* w = Wr + (size_t)c * 8;
        float xs[4] = {xv.x, xv.y, xv.z, xv.w};
#pragma unroll
        for (int q = 0; q < 4; ++q)
#pragma unroll
            for (int e = 0; e < 8; ++e) p[e] += xs[q] * w[q * 8 + e];
    }
#pragma unroll
    for (int e = 0; e < 8; ++e)
#pragma unroll
        for (int off = 32; off > 0; off >>= 1) p[e] += __shfl_down(p[e], off);
    if (lane == 0) {
        float mx = p[0];
#pragma unroll
        for (int e = 1; e < 8; ++e) mx = fmaxf(mx, p[e]);
        float ex[8];
#pragma unroll
        for (int e = 0; e < 8; ++e) ex[e] = __expf(p[e] - mx);
        int i1 = 0;
#pragma unroll
        for (int e = 1; e < 8; ++e) if (ex[e] > ex[i1]) i1 = e;
        int i2 = (i1 == 0) ? 1 : 0;
#pragma unroll
        for (int e = 0; e < 8; ++e) if (e != i1 && ex[e] > ex[i2]) i2 = e;
        float s2 = ex[i1] + ex[i2];
        float g1 = ex[i1] / s2, g2 = ex[i2] / s2;
        int pos1 = atomicAdd(&counts[i1], 1);
        tok_list[i1 * N_TOK + pos1] = token;
        gate_list[i1 * N_TOK + pos1] = g1;
        ent[token * 2] = (i1 << 16) | pos1;
        int pos2 = atomicAdd(&counts[i2], 1);
        tok_list[i2 * N_TOK + pos2] = token;
        gate_list[i2 * N_TOK + pos2] = g2;
        ent[token * 2 + 1] = (i2 << 16) | pos2;
    }
}

__global__ void offsets_k(const int* __restrict__ counts, int* __restrict__ offs) {
    if (threadIdx.x == 0) {
        int a = 0;
        for (int e = 0; e < 8; ++e) { offs[e] = a; a += counts[e]; }
    }
}

// ---------------- GEMM: D = A[M,K] @ B[K,N], B given transposed [N,K] bf16 ----------------
// MODE 0: fc   -> H[off+m, n] = bf16(gelu(acc + bias[n]));  A rows gathered via tok_list if given
// MODE 1: proj direct -> Out[m, n] = acc + bias[n]  (fp32 store)
// MODE 2: proj routed -> Rout[off+m, n] = gate[m] * (acc + bias[n]); A rows = off+m
template <int MODE>
__global__ __launch_bounds__(256) void gemm_k(
    const short* __restrict__ Abase, const short* __restrict__ Bbase,
    const float* __restrict__ biasbase, void* __restrict__ OutP,
    const int* __restrict__ counts, const int* __restrict__ offsets,
    const int* __restrict__ tok_base, const float* __restrict__ gate_base,
    int Mconst, int K, int N) {
    const int e = blockIdx.z;
    const int count = counts ? counts[e] : Mconst;
    const int mt = blockIdx.y;
    if (mt * 128 >= count) return;
    const int off = offsets ? offsets[e] : 0;
    const int n0 = blockIdx.x * 128, m0 = mt * 128;
    const short* Bm = Bbase + (size_t)e * (size_t)K * (size_t)N;
    const float* bias = biasbase + (size_t)e * (size_t)N;
    const int tid = threadIdx.x;
    const int sr = tid >> 2, sq = tid & 3;

    __shared__ __align__(16) short As[128 * 56];
    __shared__ __align__(16) short Bs[128 * 56];

    // resolve A row indices for staging (loop-invariant)
    int am0 = m0 + sr, am1 = m0 + sr + 64;
    int cm0 = min(am0, count - 1), cm1 = min(am1, count - 1);
    size_t ga0, ga1;
    if (MODE == 0) {
        if (tok_base) {
            const int* list = tok_base + e * N_TOK;
            ga0 = (size_t)list[cm0];
            ga1 = (size_t)list[cm1];
        } else {
            ga0 = (size_t)cm0; ga1 = (size_t)cm1;
        }
    } else if (MODE == 1) {
        ga0 = (size_t)cm0; ga1 = (size_t)cm1;
    } else {
        ga0 = (size_t)(off + cm0); ga1 = (size_t)(off + cm1);
    }
    const int4* aptr0 = (const int4*)(Abase + ga0 * K + sq * 8);
    const int4* aptr1 = (const int4*)(Abase + ga1 * K + sq * 8);
    const int4* bptr0 = (const int4*)(Bm + (size_t)(n0 + sr) * K + sq * 8);
    const int4* bptr1 = (const int4*)(Bm + (size_t)(n0 + sr + 64) * K + sq * 8);
    int4* asw0 = (int4*)&As[sr * 56 + sq * 8];
    int4* asw1 = (int4*)&As[(sr + 64) * 56 + sq * 8];
    int4* bsw0 = (int4*)&Bs[sr * 56 + sq * 8];
    int4* bsw1 = (int4*)&Bs[(sr + 64) * 56 + sq * 8];

    const int wave = tid >> 6, lane = tid & 63;
    const int wm = (wave >> 1) * 64, wn = (wave & 1) * 64;
    const int fr = lane & 15, quad = lane >> 4;
    const short* ard[4];
    const short* brd[4];
#pragma unroll
    for (int i = 0; i < 4; ++i) {
        ard[i] = &As[(wm + i * 16 + fr) * 56 + quad * 8];
        brd[i] = &Bs[(wn + i * 16 + fr) * 56 + quad * 8];
    }

    floatx4 acc[4][4];
#pragma unroll
    for (int i = 0; i < 4; ++i)
#pragma unroll
        for (int j = 0; j < 4; ++j) acc[i][j] = (floatx4){0.f, 0.f, 0.f, 0.f};

    const int kIters = K / 32;
    for (int kk = 0; kk < kIters; ++kk) {
        int4 av0 = *aptr0; aptr0 += 4;
        int4 av1 = *aptr1; aptr1 += 4;
        int4 bv0 = *bptr0; bptr0 += 4;
        int4 bv1 = *bptr1; bptr1 += 4;
        __syncthreads();
        *asw0 = av0; *asw1 = av1; *bsw0 = bv0; *bsw1 = bv1;
        __syncthreads();
        bf16x8 af[4], bfv[4];
#pragma unroll
        for (int i = 0; i < 4; ++i) af[i] = *(const bf16x8*)ard[i];
#pragma unroll
        for (int j = 0; j < 4; ++j) bfv[j] = *(const bf16x8*)brd[j];
#pragma unroll
        for (int i = 0; i < 4; ++i)
#pragma unroll
            for (int j = 0; j < 4; ++j)
                acc[i][j] = __builtin_amdgcn_mfma_f32_16x16x32_bf16(af[i], bfv[j], acc[i][j], 0, 0, 0);
    }

    float bcol[4];
#pragma unroll
    for (int j = 0; j < 4; ++j) bcol[j] = bias[n0 + wn + j * 16 + fr];

    if (MODE == 0) {
        short* H = (short*)OutP;
#pragma unroll
        for (int i = 0; i < 4; ++i) {
            int mb = m0 + wm + i * 16 + quad * 4;
#pragma unroll
            for (int r = 0; r < 4; ++r) {
                int m = mb + r;
                if (m < count) {
                    size_t row = (size_t)(off + m) * (size_t)N;
#pragma unroll
                    for (int j = 0; j < 4; ++j) {
                        float v = acc[i][j][r] + bcol[j];
                        H[row + n0 + wn + j * 16 + fr] = f2b(gelu_f(v));
                    }
                }
            }
        }
    } else if (MODE == 1) {
        float* O = (float*)OutP;
#pragma unroll
        for (int i = 0; i < 4; ++i) {
            int mb = m0 + wm + i * 16 + quad * 4;
#pragma unroll
            for (int r = 0; r < 4; ++r) {
                int m = mb + r;
                size_t row = (size_t)m * (size_t)N;
#pragma unroll
                for (int j = 0; j < 4; ++j) {
                    O[row + n0 + wn + j * 16 + fr] = acc[i][j][r] + bcol[j];
                }
            }
        }
    } else {
        float* R = (float*)OutP;
        const float* gate = gate_base + e * N_TOK;
#pragma unroll
        for (int i = 0; i < 4; ++i) {
            int mb = m0 + wm + i * 16 + quad * 4;
#pragma unroll
            for (int r = 0; r < 4; ++r) {
                int m = mb + r;
                if (m < count) {
                    float g = gate[m];
                    size_t row = (size_t)(off + m) * (size_t)N;
#pragma unroll
                    for (int j = 0; j < 4; ++j) {
                        float v = acc[i][j][r] + bcol[j];
                        R[row + n0 + wn + j * 16 + fr] = g * v;
                    }
                }
            }
        }
    }
}

// ---------------- combine: out[t] += rout[entry0(t)] + rout[entry1(t)] ----------------
__global__ void combine_k(float* __restrict__ out, const float* __restrict__ rout,
                          const int* __restrict__ ent, const int* __restrict__ offs) {
    int idx = blockIdx.x * 256 + threadIdx.x;
    int t = idx >> 8;
    int c4 = (idx & 255) * 4;
    int p0 = ent[t * 2], p1 = ent[t * 2 + 1];
    int m0 = offs[p0 >> 16] + (p0 & 0xFFFF);
    int m1 = offs[p1 >> 16] + (p1 & 0xFFFF);
    float4 o = *(float4*)(out + (size_t)t * 1024 + c4);
    float4 a = *(const float4*)(rout + (size_t)m0 * 1024 + c4);
    float4 b = *(const float4*)(rout + (size_t)m1 * 1024 + c4);
    o.x += a.x + b.x; o.y += a.y + b.y; o.z += a.z + b.z; o.w += a.w + b.w;
    *(float4*)(out + (size_t)t * 1024 + c4) = o;
}

extern "C" void kernel_launch(void* const* d_in, const int* in_sizes, int n_in,
                              void* d_out, int out_size, void* d_ws, size_t ws_size,
                              hipStream_t stream) {
    const float* x       = (const float*)d_in[0];
    const float* Wfc_s   = (const float*)d_in[1];
    const float* bfc_s   = (const float*)d_in[2];
    const float* Wproj_s = (const float*)d_in[3];
    const float* bproj_s = (const float*)d_in[4];
    const float* Wr      = (const float*)d_in[5];
    const float* Wfc     = (const float*)d_in[6];
    const float* bfc     = (const float*)d_in[7];
    const float* Wproj   = (const float*)d_in[8];
    const float* bproj   = (const float*)d_in[9];
    float* out = (float*)d_out;

    char* p = (char*)d_ws;
    short* xb      = (short*)p; p += (size_t)N_TOK * C_DIM * 2;          // 16.8 MB
    short* WfcsT   = (short*)p; p += (size_t)C_DIM * H_DIM * 2;          // 8.4 MB
    short* WprojsT = (short*)p; p += (size_t)C_DIM * H_DIM * 2;          // 8.4 MB
    short* WfcT    = (short*)p; p += (size_t)N_EXP * C_DIM * H_DIM * 2;  // 67 MB
    short* WprojT  = (short*)p; p += (size_t)N_EXP * C_DIM * H_DIM * 2;  // 67 MB
    short* h       = (short*)p; p += (size_t)2 * N_TOK * H_DIM * 2;      // 134 MB (reused shared->routed)
    float* rout    = (float*)p; p += (size_t)2 * N_TOK * C_DIM * 4;      // 67 MB
    int*   counts  = (int*)p;   p += 128;
    int*   offs    = (int*)p;   p += 128;
    int*   tok_list  = (int*)p;   p += (size_t)N_EXP * N_TOK * 4;        // 256 KB
    float* gate_list = (float*)p; p += (size_t)N_EXP * N_TOK * 4;        // 256 KB
    int*   ent     = (int*)p;   p += (size_t)N_TOK * 2 * 4;              // 64 KB

    hipMemsetAsync(counts, 0, 32, stream);
    cast_x_k<<<8192, 256, 0, stream>>>(x, xb);
    transpose_cast_k<<<dim3(128, 32, 1), dim3(32, 8), 0, stream>>>(Wfc_s, WfcsT, 1024, 4096);
    transpose_cast_k<<<dim3(32, 128, 1), dim3(32, 8), 0, stream>>>(Wproj_s, WprojsT, 4096, 1024);
    transpose_cast_k<<<dim3(128, 32, 8), dim3(32, 8), 0, stream>>>(Wfc, WfcT, 1024, 4096);
    transpose_cast_k<<<dim3(32, 128, 8), dim3(32, 8), 0, stream>>>(Wproj, WprojT, 4096, 1024);
    router_k<<<2048, 256, 0, stream>>>(x, Wr, counts, tok_list, gate_list, ent);
    offsets_k<<<1, 64, 0, stream>>>(counts, offs);

    // shared expert: fc (gelu) -> h rows [0,8192), then proj -> out (direct store)
    gemm_k<0><<<dim3(32, 64, 1), 256, 0, stream>>>(xb, WfcsT, bfc_s, h,
                                                   nullptr, nullptr, nullptr, nullptr,
                                                   8192, C_DIM, H_DIM);
    gemm_k<1><<<dim3(8, 64, 1), 256, 0, stream>>>(h, WprojsT, bproj_s, out,
                                                  nullptr, nullptr, nullptr, nullptr,
                                                  8192, H_DIM, C_DIM);
    // routed experts (batched over z): fc -> h rows [offs[e]+m), proj -> rout (gate-scaled)
    gemm_k<0><<<dim3(32, 64, 8), 256, 0, stream>>>(xb, WfcT, bfc, h,
                                                   counts, offs, tok_list, nullptr,
                                                   8192, C_DIM, H_DIM);
    gemm_k<2><<<dim3(8, 64, 8), 256, 0, stream>>>(h, WprojT, bproj, rout,
                                                  counts, offs, nullptr, gate_list,
                                                  8192, H_DIM, C_DIM);
    combine_k<<<8192, 256, 0, stream>>>(out, rout, ent, offs);
}

// Round 2
// 1317.210 us; speedup vs baseline: 1.0049x; 1.0049x over previous
//
#include <hip/hip_runtime.h>
#include <stdint.h>

#define N_TOK 8192
#define C_DIM 1024
#define H_DIM 4096
#define N_EXP 8

typedef __bf16 bf16x8 __attribute__((ext_vector_type(8)));
typedef float floatx4 __attribute__((ext_vector_type(4)));

__device__ __forceinline__ short f2b(float f) {
    unsigned u = __float_as_uint(f);
    unsigned r = (u + 0x7FFFu + ((u >> 16) & 1u)) >> 16;
    return (short)(r & 0xFFFFu);
}

__device__ __forceinline__ float gelu_f(float x) {
    const float c = 0.7978845608028654f;  // sqrt(2/pi)
    float u = c * (x + 0.044715f * x * x * x);
    float a = fabsf(u);
    float e = __expf(-2.0f * a);
    float t = (1.0f - e) / (1.0f + e);  // tanh(|u|), safe for large |u|
    return 0.5f * x * (1.0f + copysignf(t, u));
}

// async global->LDS, 16B per lane; lds dest is wave-uniform base + lane*16
__device__ __forceinline__ void gl_lds16(const short* g, short* l) {
    __builtin_amdgcn_global_load_lds(
        (const __attribute__((address_space(1))) unsigned int*)g,
        (__attribute__((address_space(3))) unsigned int*)l, 16, 0, 0);
}

// ---------------- cast x (fp32 -> bf16 bits) ----------------
__global__ void cast_x_k(const float* __restrict__ in, short* __restrict__ out) {
    int i = (blockIdx.x * 256 + threadIdx.x) * 4;
    float4 v = *(const float4*)(in + i);
    short4 o;
    o.x = f2b(v.x); o.y = f2b(v.y); o.z = f2b(v.z); o.w = f2b(v.w);
    *(short4*)(out + i) = o;
}

// ------------- transpose + cast weights: W[K,N] fp32 -> WT[N,K] bf16 -------------
__global__ void transpose_cast_k(const float* __restrict__ W, short* __restrict__ WT,
                                 int K, int N) {
    __shared__ float tile[32][33];
    size_t moff = (size_t)blockIdx.z * (size_t)K * (size_t)N;
    int n0 = blockIdx.x * 32, k0 = blockIdx.y * 32;
    int tx = threadIdx.x, ty = threadIdx.y;  // (32, 8)
#pragma unroll
    for (int j = 0; j < 32; j += 8)
        tile[ty + j][tx] = W[moff + (size_t)(k0 + ty + j) * N + n0 + tx];
    __syncthreads();
#pragma unroll
    for (int j = 0; j < 32; j += 8)
        WT[moff + (size_t)(n0 + ty + j) * K + k0 + tx] = f2b(tile[tx][ty + j]);
}

// ---------------- router: logits, softmax, top2, expert lists ----------------
__global__ void router_k(const float* __restrict__ x, const float* __restrict__ Wr,
                         int* __restrict__ counts, int* __restrict__ tok_list,
                         float* __restrict__ gate_list, int* __restrict__ ent) {
    int token = blockIdx.x * 4 + (threadIdx.x >> 6);
    int lane = threadIdx.x & 63;
    const float* xr = x + (size_t)token * C_DIM;
    float p[8];
#pragma unroll
    for (int e = 0; e < 8; ++e) p[e] = 0.f;
    for (int jj = 0; jj < 4; ++jj) {
        int c = (jj * 64 + lane) * 4;
        float4 xv = *(const float4*)(xr + c);
        const float* w = Wr + (size_t)c * 8;
        float xs[4] = {xv.x, xv.y, xv.z, xv.w};
#pragma unroll
        for (int q = 0; q < 4; ++q)
#pragma unroll
            for (int e = 0; e < 8; ++e) p[e] += xs[q] * w[q * 8 + e];
    }
#pragma unroll
    for (int e = 0; e < 8; ++e)
#pragma unroll
        for (int off = 32; off > 0; off >>= 1) p[e] += __shfl_down(p[e], off);
    if (lane == 0) {
        float mx = p[0];
#pragma unroll
        for (int e = 1; e < 8; ++e) mx = fmaxf(mx, p[e]);
        float ex[8];
#pragma unroll
        for (int e = 0; e < 8; ++e) ex[e] = __expf(p[e] - mx);
        int i1 = 0;
#pragma unroll
        for (int e = 1; e < 8; ++e) if (ex[e] > ex[i1]) i1 = e;
        int i2 = (i1 == 0) ? 1 : 0;
#pragma unroll
        for (int e = 0; e < 8; ++e) if (e != i1 && ex[e] > ex[i2]) i2 = e;
        float s2 = ex[i1] + ex[i2];
        float g1 = ex[i1] / s2, g2 = ex[i2] / s2;
        int pos1 = atomicAdd(&counts[i1], 1);
        tok_list[i1 * N_TOK + pos1] = token;
        gate_list[i1 * N_TOK + pos1] = g1;
        ent[token * 2] = (i1 << 16) | pos1;
        int pos2 = atomicAdd(&counts[i2], 1);
        tok_list[i2 * N_TOK + pos2] = token;
        gate_list[i2 * N_TOK + pos2] = g2;
        ent[token * 2 + 1] = (i2 << 16) | pos2;
    }
}

__global__ void offsets_k(const int* __restrict__ counts, int* __restrict__ offs) {
    if (threadIdx.x == 0) {
        int a = 0;
        for (int e = 0; e < 8; ++e) { offs[e] = a; a += counts[e]; }
    }
}

// ---------------- GEMM: D = A[M,K] @ B[K,N], B given transposed [N,K] bf16 ----------------
// 128x128 tile, BK=32, async global_load_lds staging, XOR-swizzled LDS (no pad).
// MODE 0: fc   -> H[off+m, n] = bf16(gelu(acc + bias[n]));  A rows gathered via tok_list if given
// MODE 1: proj direct -> Out[m, n] = acc + bias[n]  (fp32 store)
// MODE 2: proj routed -> Rout[off+m, n] = gate[m] * (acc + bias[n]); A rows = off+m
#define SWZ(r) (((r) ^ ((r) >> 2)) & 3)
template <int MODE>
__global__ __launch_bounds__(256) void gemm_k(
    const short* __restrict__ Abase, const short* __restrict__ Bbase,
    const float* __restrict__ biasbase, void* __restrict__ OutP,
    const int* __restrict__ counts, const int* __restrict__ offsets,
    const int* __restrict__ tok_base, const float* __restrict__ gate_base,
    int Mconst, int K, int N) {
    const int e = blockIdx.z;
    const int count = counts ? counts[e] : Mconst;
    // block swizzle: groups of 8 m-tiles share B/A tiles for L2/L3 locality
    const int nTiles = gridDim.x;
    int bid = blockIdx.y * nTiles + blockIdx.x;
    const int perGroup = 8 * nTiles;
    int group = bid / perGroup;
    int rem = bid - group * perGroup;
    const int mt = group * 8 + (rem & 7);
    const int nt = rem >> 3;
    if (mt * 128 >= count) return;
    const int off = offsets ? offsets[e] : 0;
    const int n0 = nt * 128, m0 = mt * 128;
    const short* Bm = Bbase + (size_t)e * (size_t)K * (size_t)N;
    const float* bias = biasbase + (size_t)e * (size_t)N;
    const int tid = threadIdx.x;
    const int wave = tid >> 6, lane = tid & 63;

    __shared__ __align__(16) short As[128 * 32];
    __shared__ __align__(16) short Bs[128 * 32];

    // ---- staging setup: each wave stages 32 rows of A and 32 rows of B per k-iter
    // lane covers tile rows r0 = wave*32 + lane/4 and r1 = r0+16; 16B chunk (lane&3), XOR-swizzled
    const int r0 = wave * 32 + (lane >> 2), r1 = r0 + 16;
    const int ca0 = ((lane & 3) ^ SWZ(r0)) * 8;  // shorts offset within 32-short k window
    const int ca1 = ((lane & 3) ^ SWZ(r1)) * 8;

    int am0 = min(m0 + r0, count - 1), am1 = min(m0 + r1, count - 1);
    size_t ga0, ga1;
    if (MODE == 0) {
        if (tok_base) {
            const int* list = tok_base + e * N_TOK;
            ga0 = (size_t)list[am0];
            ga1 = (size_t)list[am1];
        } else {
            ga0 = (size_t)am0; ga1 = (size_t)am1;
        }
    } else if (MODE == 1) {
        ga0 = (size_t)am0; ga1 = (size_t)am1;
    } else {
        ga0 = (size_t)(off + am0); ga1 = (size_t)(off + am1);
    }
    const short* agp0 = Abase + ga0 * K + ca0;
    const short* agp1 = Abase + ga1 * K + ca1;
    const short* bgp0 = Bm + (size_t)(n0 + r0) * K + ca0;
    const short* bgp1 = Bm + (size_t)(n0 + r1) * K + ca1;
    short* asw0 = &As[(wave * 32) * 32];
    short* asw1 = &As[(wave * 32 + 16) * 32];
    short* bsw0 = &Bs[(wave * 32) * 32];
    short* bsw1 = &Bs[(wave * 32 + 16) * 32];

    // ---- fragment read addresses (loop-invariant, swizzle-corrected)
    const int wm = (wave >> 1) * 64, wn = (wave & 1) * 64;
    const int fr = lane & 15, quad = lane >> 4;
    const short* ard[4];
    const short* brd[4];
#pragma unroll
    for (int i = 0; i < 4; ++i) {
        int ra = wm + i * 16 + fr;
        int rb = wn + i * 16 + fr;
        ard[i] = &As[ra * 32 + ((quad ^ SWZ(ra)) << 3)];
        brd[i] = &Bs[rb * 32 + ((quad ^ SWZ(rb)) << 3)];
    }

    floatx4 acc[4][4];
#pragma unroll
    for (int i = 0; i < 4; ++i)
#pragma unroll
        for (int j = 0; j < 4; ++j) acc[i][j] = (floatx4){0.f, 0.f, 0.f, 0.f};

    const int kIters = K / 32;
    for (int kk = 0; kk < kIters; ++kk) {
        __syncthreads();  // previous iter's fragment reads complete
        gl_lds16(agp0, asw0);
        gl_lds16(agp1, asw1);
        gl_lds16(bgp0, bsw0);
        gl_lds16(bgp1, bsw1);
        agp0 += 32; agp1 += 32; bgp0 += 32; bgp1 += 32;
        __syncthreads();  // drains vmcnt: staged data visible
        bf16x8 af[4], bfv[4];
#pragma unroll
        for (int i = 0; i < 4; ++i) af[i] = *(const bf16x8*)ard[i];
#pragma unroll
        for (int j = 0; j < 4; ++j) bfv[j] = *(const bf16x8*)brd[j];
#pragma unroll
        for (int i = 0; i < 4; ++i)
#pragma unroll
            for (int j = 0; j < 4; ++j)
                acc[i][j] = __builtin_amdgcn_mfma_f32_16x16x32_bf16(af[i], bfv[j], acc[i][j], 0, 0, 0);
    }

    float bcol[4];
#pragma unroll
    for (int j = 0; j < 4; ++j) bcol[j] = bias[n0 + wn + j * 16 + fr];

    if (MODE == 0) {
        short* H = (short*)OutP;
#pragma unroll
        for (int i = 0; i < 4; ++i) {
            int mb = m0 + wm + i * 16 + quad * 4;
#pragma unroll
            for (int r = 0; r < 4; ++r) {
                int m = mb + r;
                if (m < count) {
                    size_t row = (size_t)(off + m) * (size_t)N;
#pragma unroll
                    for (int j = 0; j < 4; ++j) {
                        float v = acc[i][j][r] + bcol[j];
                        H[row + n0 + wn + j * 16 + fr] = f2b(gelu_f(v));
                    }
                }
            }
        }
    } else if (MODE == 1) {
        float* O = (float*)OutP;
#pragma unroll
        for (int i = 0; i < 4; ++i) {
            int mb = m0 + wm + i * 16 + quad * 4;
#pragma unroll
            for (int r = 0; r < 4; ++r) {
                int m = mb + r;
                size_t row = (size_t)m * (size_t)N;
#pragma unroll
                for (int j = 0; j < 4; ++j) {
                    O[row + n0 + wn + j * 16 + fr] = acc[i][j][r] + bcol[j];
                }
            }
        }
    } else {
        float* R = (float*)OutP;
        const float* gate = gate_base + e * N_TOK;
#pragma unroll
        for (int i = 0; i < 4; ++i) {
            int mb = m0 + wm + i * 16 + quad * 4;
#pragma unroll
            for (int r = 0; r < 4; ++r) {
                int m = mb + r;
                if (m < count) {
                    float g = gate[m];
                    size_t row = (size_t)(off + m) * (size_t)N;
#pragma unroll
                    for (int j = 0; j < 4; ++j) {
                        float v = acc[i][j][r] + bcol[j];
                        R[row + n0 + wn + j * 16 + fr] = g * v;
                    }
                }
            }
        }
    }
}

// ---------------- combine: out[t] += rout[entry0(t)] + rout[entry1(t)] ----------------
__global__ void combine_k(float* __restrict__ out, const float* __restrict__ rout,
                          const int* __restrict__ ent, const int* __restrict__ offs) {
    int idx = blockIdx.x * 256 + threadIdx.x;
    int t = idx >> 8;
    int c4 = (idx & 255) * 4;
    int p0 = ent[t * 2], p1 = ent[t * 2 + 1];
    int m0 = offs[p0 >> 16] + (p0 & 0xFFFF);
    int m1 = offs[p1 >> 16] + (p1 & 0xFFFF);
    float4 o = *(float4*)(out + (size_t)t * 1024 + c4);
    float4 a = *(const float4*)(rout + (size_t)m0 * 1024 + c4);
    float4 b = *(const float4*)(rout + (size_t)m1 * 1024 + c4);
    o.x += a.x + b.x; o.y += a.y + b.y; o.z += a.z + b.z; o.w += a.w + b.w;
    *(float4*)(out + (size_t)t * 1024 + c4) = o;
}

extern "C" void kernel_launch(void* const* d_in, const int* in_sizes, int n_in,
                              void* d_out, int out_size, void* d_ws, size_t ws_size,
                              hipStream_t stream) {
    const float* x       = (const float*)d_in[0];
    const float* Wfc_s   = (const float*)d_in[1];
    const float* bfc_s   = (const float*)d_in[2];
    const float* Wproj_s = (const float*)d_in[3];
    const float* bproj_s = (const float*)d_in[4];
    const float* Wr      = (const float*)d_in[5];
    const float* Wfc     = (const float*)d_in[6];
    const float* bfc     = (const float*)d_in[7];
    const float* Wproj   = (const float*)d_in[8];
    const float* bproj   = (const float*)d_in[9];
    float* out = (float*)d_out;

    char* p = (char*)d_ws;
    short* xb      = (short*)p; p += (size_t)N_TOK * C_DIM * 2;          // 16.8 MB
    short* WfcsT   = (short*)p; p += (size_t)C_DIM * H_DIM * 2;          // 8.4 MB
    short* WprojsT = (short*)p; p += (size_t)C_DIM * H_DIM * 2;          // 8.4 MB
    short* WfcT    = (short*)p; p += (size_t)N_EXP * C_DIM * H_DIM * 2;  // 67 MB
    short* WprojT  = (short*)p; p += (size_t)N_EXP * C_DIM * H_DIM * 2;  // 67 MB
    short* h       = (short*)p; p += (size_t)2 * N_TOK * H_DIM * 2;      // 134 MB (reused shared->routed)
    float* rout    = (float*)p; p += (size_t)2 * N_TOK * C_DIM * 4;      // 67 MB
    int*   counts  = (int*)p;   p += 128;
    int*   offs    = (int*)p;   p += 128;
    int*   tok_list  = (int*)p;   p += (size_t)N_EXP * N_TOK * 4;        // 256 KB
    float* gate_list = (float*)p; p += (size_t)N_EXP * N_TOK * 4;        // 256 KB
    int*   ent     = (int*)p;   p += (size_t)N_TOK * 2 * 4;              // 64 KB

    hipMemsetAsync(counts, 0, 32, stream);
    cast_x_k<<<8192, 256, 0, stream>>>(x, xb);
    transpose_cast_k<<<dim3(128, 32, 1), dim3(32, 8), 0, stream>>>(Wfc_s, WfcsT, 1024, 4096);
    transpose_cast_k<<<dim3(32, 128, 1), dim3(32, 8), 0, stream>>>(Wproj_s, WprojsT, 4096, 1024);
    transpose_cast_k<<<dim3(128, 32, 8), dim3(32, 8), 0, stream>>>(Wfc, WfcT, 1024, 4096);
    transpose_cast_k<<<dim3(32, 128, 8), dim3(32, 8), 0, stream>>>(Wproj, WprojT, 4096, 1024);
    router_k<<<2048, 256, 0, stream>>>(x, Wr, counts, tok_list, gate_list, ent);
    offsets_k<<<1, 64, 0, stream>>>(counts, offs);

    // shared expert: fc (gelu) -> h rows [0,8192), then proj -> out (direct store)
    gemm_k<0><<<dim3(32, 64, 1), 256, 0, stream>>>(xb, WfcsT, bfc_s, h,
                                                   nullptr, nullptr, nullptr, nullptr,
                                                   8192, C_DIM, H_DIM);
    gemm_k<1><<<dim3(8, 64, 1), 256, 0, stream>>>(h, WprojsT, bproj_s, out,
                                                  nullptr, nullptr, nullptr, nullptr,
                                                  8192, H_DIM, C_DIM);
    // routed experts (batched over z): fc -> h rows [offs[e]+m), proj -> rout (gate-scaled)
    gemm_k<0><<<dim3(32, 64, 8), 256, 0, stream>>>(xb, WfcT, bfc, h,
                                                   counts, offs, tok_list, nullptr,
                                                   8192, C_DIM, H_DIM);
    gemm_k<2><<<dim3(8, 64, 8), 256, 0, stream>>>(h, WprojT, bproj, rout,
                                                  counts, offs, nullptr, gate_list,
                                                  8192, H_DIM, C_DIM);
    combine_k<<<8192, 256, 0, stream>>>(out, rout, ent, offs);
}

// Round 3
// 1270.683 us; speedup vs baseline: 1.0417x; 1.0366x over previous
//
#include <hip/hip_runtime.h>
#include <stdint.h>

#define N_TOK 8192
#define C_DIM 1024
#define H_DIM 4096
#define N_EXP 8   // routed experts; expert 8 = shared

typedef __bf16 bf16x8 __attribute__((ext_vector_type(8)));
typedef float floatx4 __attribute__((ext_vector_type(4)));

__device__ __forceinline__ short f2b(float f) {
    unsigned u = __float_as_uint(f);
    unsigned r = (u + 0x7FFFu + ((u >> 16) & 1u)) >> 16;
    return (short)(r & 0xFFFFu);
}

// gelu(x) = 0.5x(1+tanh(c(x+0.044715x^3))) == x * sigmoid(2c(x+0.044715x^3))
// = x / (1 + exp(-2c*x - 2c*0.044715*x^3)); use exp2 + v_rcp (no IEEE divide).
__device__ __forceinline__ float gelu_fast(float x) {
    const float k1 = -2.3025850929940457f;   // -2*sqrt(2/pi)*log2(e)... folded below
    // m = (-2c*log2e)*x + (-2c*0.044715*log2e)*x^3, c=sqrt(2/pi)
    const float a1 = -2.302114597830384f;    // -2*0.7978845608*1.4426950409
    const float a3 = -0.10294096656926834f;  // a1*0.044715
    float x2 = x * x;
    float m = x * (a1 + a3 * x2);            // fma + mul
    float e = __builtin_amdgcn_exp2f(m);     // exp(-2u) ; inf for x<<0 -> rcp->0
    return x * __builtin_amdgcn_rcpf(1.0f + e);
    (void)k1;
}

// async global->LDS, 16B per lane; lds dest is wave-uniform base + lane*16
__device__ __forceinline__ void gl_lds16(const short* g, short* l) {
    __builtin_amdgcn_global_load_lds(
        (const __attribute__((address_space(1))) unsigned int*)g,
        (__attribute__((address_space(3))) unsigned int*)l, 16, 0, 0);
}

// ---------------- cast x (fp32 -> bf16 bits) ----------------
__global__ void cast_x_k(const float* __restrict__ in, short* __restrict__ out) {
    int i = (blockIdx.x * 256 + threadIdx.x) * 4;
    float4 v = *(const float4*)(in + i);
    short4 o;
    o.x = f2b(v.x); o.y = f2b(v.y); o.z = f2b(v.z); o.w = f2b(v.w);
    *(short4*)(out + i) = o;
}

// ------------- transpose + cast weights: W[K,N] fp32 -> WT[N,K] bf16 -------------
__global__ void transpose_cast_k(const float* __restrict__ W, short* __restrict__ WT,
                                 int K, int N) {
    __shared__ float tile[32][33];
    size_t moff = (size_t)blockIdx.z * (size_t)K * (size_t)N;
    int n0 = blockIdx.x * 32, k0 = blockIdx.y * 32;
    int tx = threadIdx.x, ty = threadIdx.y;  // (32, 8)
#pragma unroll
    for (int j = 0; j < 32; j += 8)
        tile[ty + j][tx] = W[moff + (size_t)(k0 + ty + j) * N + n0 + tx];
    __syncthreads();
#pragma unroll
    for (int j = 0; j < 32; j += 8)
        WT[moff + (size_t)(n0 + ty + j) * K + k0 + tx] = f2b(tile[tx][ty + j]);
}

// ---------------- init: shared expert = expert 8, identity list, gate 1 ----------------
__global__ void init_shared_k(int* __restrict__ tok_list, float* __restrict__ gate_list,
                              int* __restrict__ counts) {
    int i = blockIdx.x * 256 + threadIdx.x;
    tok_list[8 * N_TOK + i] = i;
    gate_list[8 * N_TOK + i] = 1.0f;
    if (i == 0) counts[8] = N_TOK;
}

// ---------------- router: logits, softmax, top2, expert lists ----------------
__global__ void router_k(const float* __restrict__ x, const float* __restrict__ Wr,
                         int* __restrict__ counts, int* __restrict__ tok_list,
                         float* __restrict__ gate_list, int* __restrict__ ent) {
    int token = blockIdx.x * 4 + (threadIdx.x >> 6);
    int lane = threadIdx.x & 63;
    const float* xr = x + (size_t)token * C_DIM;
    float p[8];
#pragma unroll
    for (int e = 0; e < 8; ++e) p[e] = 0.f;
    for (int jj = 0; jj < 4; ++jj) {
        int c = (jj * 64 + lane) * 4;
        float4 xv = *(const float4*)(xr + c);
        const float* w = Wr + (size_t)c * 8;
        float xs[4] = {xv.x, xv.y, xv.z, xv.w};
#pragma unroll
        for (int q = 0; q < 4; ++q)
#pragma unroll
            for (int e = 0; e < 8; ++e) p[e] += xs[q] * w[q * 8 + e];
    }
#pragma unroll
    for (int e = 0; e < 8; ++e)
#pragma unroll
        for (int off = 32; off > 0; off >>= 1) p[e] += __shfl_down(p[e], off);
    if (lane == 0) {
        float mx = p[0];
#pragma unroll
        for (int e = 1; e < 8; ++e) mx = fmaxf(mx, p[e]);
        float ex[8];
#pragma unroll
        for (int e = 0; e < 8; ++e) ex[e] = __expf(p[e] - mx);
        int i1 = 0;
#pragma unroll
        for (int e = 1; e < 8; ++e) if (ex[e] > ex[i1]) i1 = e;
        int i2 = (i1 == 0) ? 1 : 0;
#pragma unroll
        for (int e = 0; e < 8; ++e) if (e != i1 && ex[e] > ex[i2]) i2 = e;
        float s2 = ex[i1] + ex[i2];
        float g1 = ex[i1] / s2, g2 = ex[i2] / s2;
        int pos1 = atomicAdd(&counts[i1], 1);
        tok_list[i1 * N_TOK + pos1] = token;
        gate_list[i1 * N_TOK + pos1] = g1;
        ent[token * 2] = (i1 << 16) | pos1;
        int pos2 = atomicAdd(&counts[i2], 1);
        tok_list[i2 * N_TOK + pos2] = token;
        gate_list[i2 * N_TOK + pos2] = g2;
        ent[token * 2 + 1] = (i2 << 16) | pos2;
    }
}

__global__ void offsets_k(const int* __restrict__ counts, int* __restrict__ offs) {
    if (threadIdx.x == 0) {
        int a = 0;
        for (int e = 0; e < 9; ++e) { offs[e] = a; a += counts[e]; }
    }
}

// ---------------- GEMM: Out[off+m, n] = epi(A[g(m),:K] @ B_e^T + bias_e)  ----------------
// 128x128 tile, BK=32, async global_load_lds, XOR-swizzled staging, bf16 output via
// per-wave LDS repack -> dwordx4 stores.
// IS_FC: A rows gathered via tok_list[e], epi = gelu.  else: A rows = off+m, epi = *gate.
#define SWZ(r) (((r) ^ ((r) >> 2)) & 3)
template <bool IS_FC>
__global__ __launch_bounds__(256) void gemm_k(
    const short* __restrict__ Abase, const short* __restrict__ Bbase,
    const float* __restrict__ biasbase, short* __restrict__ Out,
    const int* __restrict__ counts, const int* __restrict__ offs,
    const int* __restrict__ tok_base, const float* __restrict__ gate_base,
    int K, int N) {
    const int e = blockIdx.z;
    const int count = counts[e];
    // 8x8 supertile swizzle (gy=64, gx in {8,32})
    const int gx = gridDim.x;
    int bid = blockIdx.y * gx + blockIdx.x;
    int s = bid >> 6, w = bid & 63;
    const int mt = ((s & 7) << 3) + (w >> 3);
    const int nt = ((s >> 3) << 3) + (w & 7);
    if (mt * 128 >= count) return;
    const int off = offs[e];
    const int n0 = nt * 128, m0 = mt * 128;
    const short* Bm = Bbase + (size_t)e * (size_t)K * (size_t)N;
    const float* bias = biasbase + (size_t)e * (size_t)N;
    const int tid = threadIdx.x;
    const int wave = tid >> 6, lane = tid & 63;

    __shared__ __align__(16) short smem[8192];  // 16 KB: As | Bs ; epilogue slabs
    short* As = smem;
    short* Bs = smem + 4096;

    // ---- staging: wave stages rows [wave*32, wave*32+32) of A and B tiles
    const int r0 = wave * 32 + (lane >> 2), r1 = r0 + 16;
    const int ca0 = ((lane & 3) ^ SWZ(r0)) * 8;
    const int ca1 = ((lane & 3) ^ SWZ(r1)) * 8;

    int am0 = min(m0 + r0, count - 1), am1 = min(m0 + r1, count - 1);
    size_t ga0, ga1;
    if (IS_FC) {
        const int* list = tok_base + e * N_TOK;
        ga0 = (size_t)list[am0];
        ga1 = (size_t)list[am1];
    } else {
        ga0 = (size_t)(off + am0);
        ga1 = (size_t)(off + am1);
    }
    const short* agp0 = Abase + ga0 * K + ca0;
    const short* agp1 = Abase + ga1 * K + ca1;
    const short* bgp0 = Bm + (size_t)(n0 + r0) * K + ca0;
    const short* bgp1 = Bm + (size_t)(n0 + r1) * K + ca1;
    short* asw0 = &As[(wave * 32) * 32];
    short* asw1 = &As[(wave * 32 + 16) * 32];
    short* bsw0 = &Bs[(wave * 32) * 32];
    short* bsw1 = &Bs[(wave * 32 + 16) * 32];

    // ---- fragment read addresses
    const int wm = (wave >> 1) * 64, wn = (wave & 1) * 64;
    const int fr = lane & 15, quad = lane >> 4;
    const short* ard[4];
    const short* brd[4];
#pragma unroll
    for (int i = 0; i < 4; ++i) {
        int ra = wm + i * 16 + fr;
        int rb = wn + i * 16 + fr;
        ard[i] = &As[ra * 32 + ((quad ^ SWZ(ra)) << 3)];
        brd[i] = &Bs[rb * 32 + ((quad ^ SWZ(rb)) << 3)];
    }

    floatx4 acc[4][4];
#pragma unroll
    for (int i = 0; i < 4; ++i)
#pragma unroll
        for (int j = 0; j < 4; ++j) acc[i][j] = (floatx4){0.f, 0.f, 0.f, 0.f};

    const int kIters = K / 32;
    for (int kk = 0; kk < kIters; ++kk) {
        __syncthreads();
        gl_lds16(agp0, asw0);
        gl_lds16(agp1, asw1);
        gl_lds16(bgp0, bsw0);
        gl_lds16(bgp1, bsw1);
        agp0 += 32; agp1 += 32; bgp0 += 32; bgp1 += 32;
        __syncthreads();
        bf16x8 af[4], bfv[4];
#pragma unroll
        for (int i = 0; i < 4; ++i) af[i] = *(const bf16x8*)ard[i];
#pragma unroll
        for (int j = 0; j < 4; ++j) bfv[j] = *(const bf16x8*)brd[j];
#pragma unroll
        for (int i = 0; i < 4; ++i)
#pragma unroll
            for (int j = 0; j < 4; ++j)
                acc[i][j] = __builtin_amdgcn_mfma_f32_16x16x32_bf16(af[i], bfv[j], acc[i][j], 0, 0, 0);
    }

    // ---- epilogue: per-wave LDS repack (slab 16 x 72 shorts), wide stores
    __syncthreads();  // all waves done reading As/Bs
    float bcol[4];
#pragma unroll
    for (int j = 0; j < 4; ++j) bcol[j] = bias[n0 + wn + j * 16 + fr];

    short* slab = smem + wave * 1152;
    const int rr = lane >> 2, cc = lane & 3;
    const int srow_m = m0 + wm + rr;           // +i*16 below
    short* sw = slab + quad * 288 + fr;        // + (r*72 + j*16) imm
    const short* srd = slab + rr * 72 + cc * 16;

#pragma unroll
    for (int i = 0; i < 4; ++i) {
        float g4[4];
        if (!IS_FC) {
            const float* gl = gate_base + e * N_TOK;
#pragma unroll
            for (int r = 0; r < 4; ++r) g4[r] = gl[min(m0 + wm + i * 16 + quad * 4 + r, count - 1)];
        }
#pragma unroll
        for (int j = 0; j < 4; ++j)
#pragma unroll
            for (int r = 0; r < 4; ++r) {
                float v = acc[i][j][r] + bcol[j];
                if (IS_FC) v = gelu_fast(v); else v *= g4[r];
                sw[r * 72 + j * 16] = f2b(v);
            }
        int m = srow_m + i * 16;
        if (m < count) {
            int4 v0 = *(const int4*)srd;
            int4 v1 = *(const int4*)(srd + 8);
            short* orow = Out + (size_t)(off + m) * (size_t)N + n0 + wn + cc * 16;
            *(int4*)orow = v0;
            *(int4*)(orow + 8) = v1;
        }
        __builtin_amdgcn_s_waitcnt(0);  // ensure slab reads done before next i overwrites
    }
}

// ---------------- combine: out[t] = shared_row + rout[ent0] + rout[ent1] (bf16 -> f32) ----------------
__global__ void combine_k(float* __restrict__ out, const short* __restrict__ routc,
                          const int* __restrict__ ent, const int* __restrict__ offs) {
    int tid = threadIdx.x;
    int t = blockIdx.x * 2 + (tid >> 7);
    int c = (tid & 127) * 8;
    int p0 = ent[t * 2], p1 = ent[t * 2 + 1];
    size_t r0 = (size_t)(offs[p0 >> 16] + (p0 & 0xFFFF)) * 1024 + c;
    size_t r1 = (size_t)(offs[p1 >> 16] + (p1 & 0xFFFF)) * 1024 + c;
    size_t rs = (size_t)(16384 + t) * 1024 + c;
    int4 va = *(const int4*)(routc + rs);
    int4 vb = *(const int4*)(routc + r0);
    int4 vc = *(const int4*)(routc + r1);
    float o[8];
    const int* pa = (const int*)&va;
    const int* pb = (const int*)&vb;
    const int* pc = (const int*)&vc;
#pragma unroll
    for (int q = 0; q < 4; ++q) {
        unsigned a = pa[q], b = pb[q], cw = pc[q];
        o[2 * q] = __uint_as_float(a << 16) + __uint_as_float(b << 16) + __uint_as_float(cw << 16);
        o[2 * q + 1] = __uint_as_float(a & 0xFFFF0000u) + __uint_as_float(b & 0xFFFF0000u) +
                       __uint_as_float(cw & 0xFFFF0000u);
    }
    float* op = out + (size_t)t * 1024 + c;
    *(float4*)op = (float4){o[0], o[1], o[2], o[3]};
    *(float4*)(op + 4) = (float4){o[4], o[5], o[6], o[7]};
}

extern "C" void kernel_launch(void* const* d_in, const int* in_sizes, int n_in,
                              void* d_out, int out_size, void* d_ws, size_t ws_size,
                              hipStream_t stream) {
    const float* x       = (const float*)d_in[0];
    const float* Wfc_s   = (const float*)d_in[1];
    const float* bfc_s   = (const float*)d_in[2];
    const float* Wproj_s = (const float*)d_in[3];
    const float* bproj_s = (const float*)d_in[4];
    const float* Wr      = (const float*)d_in[5];
    const float* Wfc     = (const float*)d_in[6];
    const float* bfc     = (const float*)d_in[7];
    const float* Wproj   = (const float*)d_in[8];
    const float* bproj   = (const float*)d_in[9];
    float* out = (float*)d_out;

    char* p = (char*)d_ws;
    short* xb      = (short*)p; p += (size_t)N_TOK * C_DIM * 2;              // 16.8 MB
    short* WfcT    = (short*)p; p += (size_t)9 * C_DIM * H_DIM * 2;          // 75.5 MB
    short* WprojT  = (short*)p; p += (size_t)9 * C_DIM * H_DIM * 2;          // 75.5 MB
    float* bfc_all = (float*)p; p += (size_t)9 * H_DIM * 4;                  // 147 KB
    float* bpj_all = (float*)p; p += (size_t)9 * C_DIM * 4;                  // 37 KB
    short* h       = (short*)p; p += (size_t)24576 * H_DIM * 2;              // 201 MB
    short* routc   = (short*)p; p += (size_t)24576 * C_DIM * 2;              // 50 MB
    int*   counts  = (int*)p;   p += 128;
    int*   offs    = (int*)p;   p += 128;
    int*   tok_list  = (int*)p;   p += (size_t)9 * N_TOK * 4;
    float* gate_list = (float*)p; p += (size_t)9 * N_TOK * 4;
    int*   ent     = (int*)p;   p += (size_t)N_TOK * 2 * 4;

    hipMemsetAsync(counts, 0, 64, stream);
    cast_x_k<<<8192, 256, 0, stream>>>(x, xb);
    transpose_cast_k<<<dim3(128, 32, 8), dim3(32, 8), 0, stream>>>(Wfc, WfcT, 1024, 4096);
    transpose_cast_k<<<dim3(128, 32, 1), dim3(32, 8), 0, stream>>>(Wfc_s, WfcT + (size_t)8 * C_DIM * H_DIM, 1024, 4096);
    transpose_cast_k<<<dim3(32, 128, 8), dim3(32, 8), 0, stream>>>(Wproj, WprojT, 4096, 1024);
    transpose_cast_k<<<dim3(32, 128, 1), dim3(32, 8), 0, stream>>>(Wproj_s, WprojT + (size_t)8 * C_DIM * H_DIM, 4096, 1024);
    hipMemcpyAsync(bfc_all, bfc, (size_t)8 * H_DIM * 4, hipMemcpyDeviceToDevice, stream);
    hipMemcpyAsync(bfc_all + 8 * H_DIM, bfc_s, (size_t)H_DIM * 4, hipMemcpyDeviceToDevice, stream);
    hipMemcpyAsync(bpj_all, bproj, (size_t)8 * C_DIM * 4, hipMemcpyDeviceToDevice, stream);
    hipMemcpyAsync(bpj_all + 8 * C_DIM, bproj_s, (size_t)C_DIM * 4, hipMemcpyDeviceToDevice, stream);
    init_shared_k<<<32, 256, 0, stream>>>(tok_list, gate_list, counts);
    router_k<<<2048, 256, 0, stream>>>(x, Wr, counts, tok_list, gate_list, ent);
    offsets_k<<<1, 64, 0, stream>>>(counts, offs);

    // fc: all 9 experts (8 routed + shared), gelu, bf16 h
    gemm_k<true><<<dim3(32, 64, 9), 256, 0, stream>>>(
        xb, WfcT, bfc_all, h, counts, offs, tok_list, nullptr, C_DIM, H_DIM);
    // proj: all 9 experts, gate-scaled (gate=1 for shared), bf16 routc
    gemm_k<false><<<dim3(8, 64, 9), 256, 0, stream>>>(
        h, WprojT, bpj_all, routc, counts, offs, nullptr, gate_list, H_DIM, C_DIM);
    combine_k<<<4096, 256, 0, stream>>>(out, routc, ent, offs);
}